// Round 23
// baseline (28.398 us; speedup 1.0000x reference)
//
#include <hip/hip_runtime.h>
#include <hip/hip_bf16.h>

// DualMem fast_get_image_pred:
//   logits[b,c] = 100 * (Σ_m w_m sim_m) / sqrt(Σ_{i,j} w_i w_j G[c,i,j])
//
// Lesson ledger (23 rounds):
//  - R21 vs R22 equal (22.9/22.5us) despite 2x different line-touches/CU and
//    2x different occupancy => neither line-throughput nor simple latency is
//    the limiter. Invariant: 45MB mem streamed cold each replay (the
//    harness's 268MB ws poison-fills evict L3 between replays) at only
//    8-16 waves/CU of miss concurrency -> ~2.2 TB/s effective.
//    THIS round: K-split S=2 across BLOCKS (grid 1000x2, 1 class/block,
//    LDS 16.5KB) -> ~31 waves/CU resident, ~4x outstanding misses.
//    mem still read exactly once (K-partitioned). Cost: finish dispatch +
//    6.6MB partials.
//  - Cost ladder: 57 -> 36 -> 39 -> 22.9 -> 22.5 (pack fragments, fuse,
//    K-split across waves, 2-class amortize).
//  - Spill triggers: launch_bounds 2nd arg / non-256 blocks / >=48KB LDS /
//    escaped local arrays.
//  - MFMA C-layout col=lane&15, row=(lane>>4)*4+reg (verified R12/R13).
//
// Structure (3 dispatches):
//   P1 pack_img: imgP[4][32][64] bf16x8 fragments (128 KB, L2-hot).
//   K1 fused4: grid(1000,2); block (c,kq); wave w owns ksteps
//      {16kq+4w..+3}; mem packed once, gram rides on packed regs, sim vs
//      4 b-tiles' imgP. Partials to ws. LDS 16.5 KB.
//   K2 finish: grid(250); sums 2 K-slices, logits.
//   Fallback (small ws): R21-style self-contained fused2 (1 dispatch).

constexpr int Bn = 64;     // batch
constexpr int Cn = 1000;   // classes
constexpr int Mn = 11;     // memories per class
constexpr int Dn = 1024;   // feature dim
constexpr float BETA = 5.5f;

typedef __attribute__((ext_vector_type(8))) short bf16x8;
typedef __attribute__((ext_vector_type(4))) float f32x4;

__device__ inline short f2bf(float x) {
    union { __hip_bfloat16 h; short s; } u;
    u.h = __float2bfloat16(x);
    return u.s;
}

__device__ inline bf16x8 pack_bf16x8(const float4 a, const float4 b) {
    bf16x8 r;
    r[0] = f2bf(a.x); r[1] = f2bf(a.y); r[2] = f2bf(a.z); r[3] = f2bf(a.w);
    r[4] = f2bf(b.x); r[5] = f2bf(b.y); r[6] = f2bf(b.z); r[7] = f2bf(b.w);
    return r;
}

// ---------------- P1: imgP fragments (R18-verified) ----------------
__global__ __launch_bounds__(256) void pack_img_kernel(
    const float* __restrict__ img, bf16x8* __restrict__ imgP) {
    const int t = blockIdx.x * 256 + threadIdx.x;   // 8192 chunks
    const int l = t & 63;
    const int kstep = (t >> 6) & 31;
    const int w = t >> 11;
    const int row = w * 16 + (l & 15);
    const int kcol = kstep * 32 + (l >> 4) * 8;
    const float4 a0 = *reinterpret_cast<const float4*>(img + row * Dn + kcol);
    const float4 a1 = *reinterpret_cast<const float4*>(img + row * Dn + kcol + 4);
    imgP[t] = pack_bf16x8(a0, a1);
}

// ---------------- K1: fused, K split across blocks (S=2) ----------------
__global__ __launch_bounds__(256) void fused4_kernel(
    const bf16x8* __restrict__ imgP, const float* __restrict__ mem,
    float* __restrict__ simp, float* __restrict__ gramp) {
    __shared__ float redS[4][Bn][12];   // per-wave partial sims (12 KB)
    __shared__ f32x4 redGp[4][64];      // per-wave gram partials (4 KB)

    const int c   = blockIdx.x;
    const int kq  = blockIdx.y;         // K-half
    const int tid = threadIdx.x;
    const int l   = tid & 63;
    const int w   = tid >> 6;           // wave owns ksteps {16kq+4w..+3}
    const int rw  = l & 15;
    const int mrow = (rw < Mn) ? rw : 0;   // pad rows alias row 0
    const int kb   = (l >> 4) * 8;

    const float* mc = mem + (size_t)c * (Mn * Dn) + mrow * Dn + kb;

    f32x4 sS0 = {0.f,0.f,0.f,0.f}, sS1 = {0.f,0.f,0.f,0.f};
    f32x4 sS2 = {0.f,0.f,0.f,0.f}, sS3 = {0.f,0.f,0.f,0.f};
    f32x4 gA  = {0.f,0.f,0.f,0.f};

#pragma unroll
    for (int j = 0; j < 4; ++j) {
        const int kstep = 16 * kq + 4 * w + j;
        const float4 m0 = *reinterpret_cast<const float4*>(mc + kstep * 32);
        const float4 m1 = *reinterpret_cast<const float4*>(mc + kstep * 32 + 4);
        const bf16x8 f = pack_bf16x8(m0, m1);
        gA = __builtin_amdgcn_mfma_f32_16x16x32_bf16(f, f, gA, 0, 0, 0);
        const bf16x8* p = imgP + kstep * 64 + l;
        const bf16x8 a0 = p[0];
        const bf16x8 a1 = p[2048];
        const bf16x8 a2 = p[4096];
        const bf16x8 a3 = p[6144];
        sS0 = __builtin_amdgcn_mfma_f32_16x16x32_bf16(a0, f, sS0, 0, 0, 0);
        sS1 = __builtin_amdgcn_mfma_f32_16x16x32_bf16(a1, f, sS1, 0, 0, 0);
        sS2 = __builtin_amdgcn_mfma_f32_16x16x32_bf16(a2, f, sS2, 0, 0, 0);
        sS3 = __builtin_amdgcn_mfma_f32_16x16x32_bf16(a3, f, sS3, 0, 0, 0);
    }

    // stash: C layout col=l&15 (m), row=(l>>4)*4+reg (b within tile)
    const int mcol = l & 15;
    const int r0   = (l >> 4) * 4;
    if (mcol < Mn) {
#pragma unroll
        for (int q = 0; q < 4; ++q) {
            redS[w][ 0 + r0 + q][mcol] = sS0[q];
            redS[w][16 + r0 + q][mcol] = sS1[q];
            redS[w][32 + r0 + q][mcol] = sS2[q];
            redS[w][48 + r0 + q][mcol] = sS3[q];
        }
    }
    redGp[w][l] = gA;
    __syncthreads();

    if (tid < 64) {
        // gram partial for this K-half
        const f32x4 g = redGp[0][l] + redGp[1][l] + redGp[2][l] + redGp[3][l];
        float* go = gramp + ((size_t)kq * Cn + c) * (Mn * Mn);
        if (mcol < Mn) {
            if (r0 + 0 < Mn) go[(r0 + 0) * Mn + mcol] = g[0];
            if (r0 + 1 < Mn) go[(r0 + 1) * Mn + mcol] = g[1];
            if (r0 + 2 < Mn) go[(r0 + 2) * Mn + mcol] = g[2];
            if (r0 + 3 < Mn) go[(r0 + 3) * Mn + mcol] = g[3];
        }
        // sim partial: thread b sums the 4 waves
        const int b = tid;
        float* so = simp + ((size_t)kq * Cn + c) * (Bn * Mn) + b * Mn;
#pragma unroll
        for (int m = 0; m < Mn; ++m)
            so[m] = redS[0][b][m] + redS[1][b][m] + redS[2][b][m] + redS[3][b][m];
    }
}

// ---------------- K2: finish (sums 2 K-slices) ----------------
__global__ __launch_bounds__(256) void finish_kernel(
    const float* __restrict__ simp, const float* __restrict__ gramp,
    float* __restrict__ out) {
    const int b = threadIdx.x & 63;
    const int c = blockIdx.x * 4 + (threadIdx.x >> 6);

    const float* sp = simp + (size_t)c * (Bn * Mn) + b * Mn;
    const float* gp = gramp + (size_t)c * (Mn * Mn);
    constexpr size_t SIMSTR  = (size_t)Cn * Bn * Mn;
    constexpr size_t GRAMSTR = (size_t)Cn * Mn * Mn;

    float wv[Mn];
    float numer = 0.f;
#pragma unroll
    for (int m = 0; m < Mn; ++m) {
        const float s = sp[m] + sp[SIMSTR + m];
        wv[m] = __expf(BETA * (s - 1.f));
        numer = fmaf(wv[m], s, numer);
    }
    float den2 = 0.f;
#pragma unroll
    for (int i = 0; i < Mn; ++i) {
        float row = 0.f;
#pragma unroll
        for (int j = 0; j < Mn; ++j) {
            const float Gv = gp[i * Mn + j] + gp[GRAMSTR + i * Mn + j];
            row = fmaf(wv[j], Gv, row);
        }
        den2 = fmaf(wv[i], row, den2);
    }
    out[b * Cn + c] = 100.f * numer / sqrtf(den2);
}

// ---------------- fallback: self-contained single-dispatch (R21-style) ----------------
__global__ __launch_bounds__(256) void fused2_kernel(
    const float* __restrict__ img, const float* __restrict__ mem,
    float* __restrict__ out) {
    __shared__ float redS[4][Bn][12];
    __shared__ f32x4 redGp[4][64];
    __shared__ float redG[Mn * Mn];

    const int c   = blockIdx.x;
    const int tid = threadIdx.x;
    const int l   = tid & 63;
    const int w   = tid >> 6;
    const int rw  = l & 15;
    const int mrow = (rw < Mn) ? rw : 0;
    const int kb   = (l >> 4) * 8;

    const float* mc = mem + (size_t)c * (Mn * Dn) + mrow * Dn + kb;

    f32x4 accS0 = {0.f,0.f,0.f,0.f}, accS1 = {0.f,0.f,0.f,0.f};
    f32x4 accS2 = {0.f,0.f,0.f,0.f}, accS3 = {0.f,0.f,0.f,0.f};
    f32x4 accG  = {0.f,0.f,0.f,0.f};

#pragma unroll
    for (int j = 0; j < 8; ++j) {
        const int kstep = 8 * w + j;
        const float4 m0 = *reinterpret_cast<const float4*>(mc + kstep * 32);
        const float4 m1 = *reinterpret_cast<const float4*>(mc + kstep * 32 + 4);
        const bf16x8 f = pack_bf16x8(m0, m1);
        accG = __builtin_amdgcn_mfma_f32_16x16x32_bf16(f, f, accG, 0, 0, 0);
        const float* ic = img + rw * Dn + kstep * 32 + kb;
        const float4 i00 = *reinterpret_cast<const float4*>(ic);
        const float4 i01 = *reinterpret_cast<const float4*>(ic + 4);
        const float4 i10 = *reinterpret_cast<const float4*>(ic + 16 * Dn);
        const float4 i11 = *reinterpret_cast<const float4*>(ic + 16 * Dn + 4);
        const float4 i20 = *reinterpret_cast<const float4*>(ic + 32 * Dn);
        const float4 i21 = *reinterpret_cast<const float4*>(ic + 32 * Dn + 4);
        const float4 i30 = *reinterpret_cast<const float4*>(ic + 48 * Dn);
        const float4 i31 = *reinterpret_cast<const float4*>(ic + 48 * Dn + 4);
        const bf16x8 a0 = pack_bf16x8(i00, i01);
        const bf16x8 a1 = pack_bf16x8(i10, i11);
        const bf16x8 a2 = pack_bf16x8(i20, i21);
        const bf16x8 a3 = pack_bf16x8(i30, i31);
        accS0 = __builtin_amdgcn_mfma_f32_16x16x32_bf16(a0, f, accS0, 0, 0, 0);
        accS1 = __builtin_amdgcn_mfma_f32_16x16x32_bf16(a1, f, accS1, 0, 0, 0);
        accS2 = __builtin_amdgcn_mfma_f32_16x16x32_bf16(a2, f, accS2, 0, 0, 0);
        accS3 = __builtin_amdgcn_mfma_f32_16x16x32_bf16(a3, f, accS3, 0, 0, 0);
    }

    const int mcol = l & 15;
    const int r0   = (l >> 4) * 4;
    if (mcol < Mn) {
#pragma unroll
        for (int q = 0; q < 4; ++q) {
            redS[w][ 0 + r0 + q][mcol] = accS0[q];
            redS[w][16 + r0 + q][mcol] = accS1[q];
            redS[w][32 + r0 + q][mcol] = accS2[q];
            redS[w][48 + r0 + q][mcol] = accS3[q];
        }
    }
    redGp[w][l] = accG;
    __syncthreads();

    if (tid < 64) {
        const f32x4 g = redGp[0][l] + redGp[1][l] + redGp[2][l] + redGp[3][l];
        if (mcol < Mn) {
            if (r0 + 0 < Mn) redG[(r0 + 0) * Mn + mcol] = g[0];
            if (r0 + 1 < Mn) redG[(r0 + 1) * Mn + mcol] = g[1];
            if (r0 + 2 < Mn) redG[(r0 + 2) * Mn + mcol] = g[2];
            if (r0 + 3 < Mn) redG[(r0 + 3) * Mn + mcol] = g[3];
        }
    }
    __syncthreads();

    if (tid < Bn) {
        const int b = tid;
        float wv[Mn];
        float numer = 0.f;
#pragma unroll
        for (int m = 0; m < Mn; ++m) {
            const float s = redS[0][b][m] + redS[1][b][m]
                          + redS[2][b][m] + redS[3][b][m];
            wv[m] = __expf(BETA * (s - 1.f));
            numer = fmaf(wv[m], s, numer);
        }
        float den2 = 0.f;
#pragma unroll
        for (int i = 0; i < Mn; ++i) {
            float row = 0.f;
#pragma unroll
            for (int j = 0; j < Mn; ++j) row = fmaf(wv[j], redG[i * Mn + j], row);
            den2 = fmaf(wv[i], row, den2);
        }
        out[b * Cn + c] = 100.f * numer / sqrtf(den2);
    }
}

extern "C" void kernel_launch(void* const* d_in, const int* in_sizes, int n_in,
                              void* d_out, int out_size, void* d_ws, size_t ws_size,
                              hipStream_t stream) {
    const float* img = (const float*)d_in[0];  // [64][1024] f32
    const float* mem = (const float*)d_in[1];  // [1000][11][1024] f32
    float* out = (float*)d_out;                // [64][1000] f32
    (void)in_sizes; (void)n_in; (void)out_size;

    constexpr size_t IMGP_B  = (size_t)4 * 32 * 64 * 16;          // 128 KB
    constexpr size_t SIMP_B  = (size_t)2 * Cn * Bn * Mn * 4;      // 5.63 MB
    constexpr size_t GRAMP_B = (size_t)2 * Cn * Mn * Mn * 4;      // 0.97 MB

    char* base = (char*)d_ws;
    const size_t need = IMGP_B + SIMP_B + GRAMP_B;                // ~6.7 MB

    if (ws_size >= need) {
        bf16x8* imgP = (bf16x8*)base;
        float* simp  = (float*)(base + IMGP_B);
        float* gramp = (float*)(base + IMGP_B + SIMP_B);
        pack_img_kernel<<<dim3(32), dim3(256), 0, stream>>>(img, imgP);
        fused4_kernel<<<dim3(Cn, 2), dim3(256), 0, stream>>>(imgP, mem, simp, gramp);
        finish_kernel<<<dim3(Cn / 4), dim3(256), 0, stream>>>(simp, gramp, out);
    } else {
        fused2_kernel<<<dim3(Cn), dim3(256), 0, stream>>>(img, mem, out);
    }
}

// Round 24
// 22.927 us; speedup vs baseline: 1.2386x; 1.2386x over previous
//
#include <hip/hip_runtime.h>
#include <hip/hip_bf16.h>

// DualMem fast_get_image_pred:
//   logits[b,c] = 100 * (Σ_m w_m sim_m) / sqrt(Σ_{i,j} w_i w_j G[c,i,j])
//
// Lesson ledger (24 rounds):
//  - R21/R22/R23: 22.9 / 22.5 / 28.4us across 1x/0.5x/2x occupancy and
//    3 ILP structures => NOT concurrency-bound. Invariant = 45MB mem
//    streamed in FRAGMENT pattern (16 rows x 4KB apart per wave-load) ->
//    scattered 64B granules kill DRAM row-buffer locality -> ~2.2TB/s
//    effective (45MB ~= 20us = the floor). Poison-fills (268MB >= L3)
//    interleave replays, so mem is cold each replay.
//    THIS round: sequential HBM stream for mem (coalesced row-major) +
//    LDS shuffle to fragment order. K-half staging (22.7KB, row stride
//    516 floats -> rows 4 banks apart); arena aliased for the reduce
//    buffers; everything else = verified R21 structure.
//  - Spill triggers: launch_bounds 2nd arg / non-256 blocks / >=48KB LDS /
//    escaped local arrays. Arena = 23KB, live ~60-90: safe.
//  - MFMA C-layout col=lane&15, row=(lane>>4)*4+reg (verified R12/R13).
//
// Structure (2 dispatches):
//   P1 pack_img: imgP[4][32][64] bf16x8 fragments (128 KB, L2-hot).
//   K1 fused5: grid(1000); 2 K-half phases: {stage memL coalesced, barrier,
//      wave w: 4 local ksteps -> LDS fragment reads + gram + sim MFMAs};
//      then LDS reduce + in-block finish (R21-verified).
//   Fallback (ws < 128KB): R21-style self-contained fused2.

constexpr int Bn = 64;     // batch
constexpr int Cn = 1000;   // classes
constexpr int Mn = 11;     // memories per class
constexpr int Dn = 1024;   // feature dim
constexpr int LSTR = 516;  // LDS row stride (floats): rows 4 banks apart
constexpr float BETA = 5.5f;

typedef __attribute__((ext_vector_type(8))) short bf16x8;
typedef __attribute__((ext_vector_type(4))) float f32x4;

__device__ inline short f2bf(float x) {
    union { __hip_bfloat16 h; short s; } u;
    u.h = __float2bfloat16(x);
    return u.s;
}

__device__ inline bf16x8 pack_bf16x8(const float4 a, const float4 b) {
    bf16x8 r;
    r[0] = f2bf(a.x); r[1] = f2bf(a.y); r[2] = f2bf(a.z); r[3] = f2bf(a.w);
    r[4] = f2bf(b.x); r[5] = f2bf(b.y); r[6] = f2bf(b.z); r[7] = f2bf(b.w);
    return r;
}

// ---------------- P1: imgP fragments (R18-verified) ----------------
__global__ __launch_bounds__(256) void pack_img_kernel(
    const float* __restrict__ img, bf16x8* __restrict__ imgP) {
    const int t = blockIdx.x * 256 + threadIdx.x;   // 8192 chunks
    const int l = t & 63;
    const int kstep = (t >> 6) & 31;
    const int w = t >> 11;
    const int row = w * 16 + (l & 15);
    const int kcol = kstep * 32 + (l >> 4) * 8;
    const float4 a0 = *reinterpret_cast<const float4*>(img + row * Dn + kcol);
    const float4 a1 = *reinterpret_cast<const float4*>(img + row * Dn + kcol + 4);
    imgP[t] = pack_bf16x8(a0, a1);
}

// ---------------- K1: fused, coalesced mem stream via LDS ----------------
__global__ __launch_bounds__(256) void fused5_kernel(
    const bf16x8* __restrict__ imgP, const float* __restrict__ mem,
    float* __restrict__ out) {
    // arena phase A: memL[11][516] f32 (22.7 KB)
    // arena phase B (after barrier): redS[4][64][12] | redGp[4][64] f32x4 | redG[121]
    __shared__ float arena[Mn * LSTR];
    float* memL  = arena;
    float* redS  = arena;                       // [4][64][12]
    f32x4* redGp = (f32x4*)(arena + 3072);      // [4][64] (16B-aligned: 12288B)
    float* redG  = arena + 3072 + 256 * 4;      // [121]

    const int c   = blockIdx.x;
    const int tid = threadIdx.x;
    const int l   = tid & 63;
    const int w   = tid >> 6;              // wave owns ksteps {16kq+4w+j}
    const int rw  = l & 15;
    const int mrow = (rw < Mn) ? rw : 0;   // pad rows alias row 0 (broadcast)
    const int kb   = (l >> 4) * 8;

    const float* mc = mem + (size_t)c * (Mn * Dn);

    f32x4 sS0 = {0.f,0.f,0.f,0.f}, sS1 = {0.f,0.f,0.f,0.f};
    f32x4 sS2 = {0.f,0.f,0.f,0.f}, sS3 = {0.f,0.f,0.f,0.f};
    f32x4 gA  = {0.f,0.f,0.f,0.f};

#pragma unroll
    for (int kq = 0; kq < 2; ++kq) {
        if (kq) __syncthreads();           // phase-0 LDS reads done
        // stage this K-half: 11 rows x 512 f32, coalesced sequential stream
        for (int u = tid; u < Mn * 128; u += 256) {
            const int row = u >> 7;
            const int c4  = (u & 127) * 4;
            const float4 v = *reinterpret_cast<const float4*>(
                mc + row * Dn + kq * 512 + c4);
            *reinterpret_cast<float4*>(&memL[row * LSTR + c4]) = v;
        }
        __syncthreads();
#pragma unroll
        for (int j = 0; j < 4; ++j) {
            const int ks = 4 * w + j;              // local kstep 0..15
            const int kstep = 16 * kq + ks;
            const float4 m0 = *reinterpret_cast<const float4*>(
                &memL[mrow * LSTR + ks * 32 + kb]);
            const float4 m1 = *reinterpret_cast<const float4*>(
                &memL[mrow * LSTR + ks * 32 + kb + 4]);
            const bf16x8 f = pack_bf16x8(m0, m1);
            gA = __builtin_amdgcn_mfma_f32_16x16x32_bf16(f, f, gA, 0, 0, 0);
            const bf16x8* p = imgP + kstep * 64 + l;
            const bf16x8 a0 = p[0];
            const bf16x8 a1 = p[2048];
            const bf16x8 a2 = p[4096];
            const bf16x8 a3 = p[6144];
            sS0 = __builtin_amdgcn_mfma_f32_16x16x32_bf16(a0, f, sS0, 0, 0, 0);
            sS1 = __builtin_amdgcn_mfma_f32_16x16x32_bf16(a1, f, sS1, 0, 0, 0);
            sS2 = __builtin_amdgcn_mfma_f32_16x16x32_bf16(a2, f, sS2, 0, 0, 0);
            sS3 = __builtin_amdgcn_mfma_f32_16x16x32_bf16(a3, f, sS3, 0, 0, 0);
        }
    }
    __syncthreads();   // all memL reads done — arena becomes reduce buffers

    // stash partials: C layout col=l&15 (m), row=(l>>4)*4+reg (b within tile)
    const int mcol = l & 15;
    const int r0   = (l >> 4) * 4;
    if (mcol < Mn) {
#pragma unroll
        for (int q = 0; q < 4; ++q) {
            redS[(w * 64 +  0 + r0 + q) * 12 + mcol] = sS0[q];
            redS[(w * 64 + 16 + r0 + q) * 12 + mcol] = sS1[q];
            redS[(w * 64 + 32 + r0 + q) * 12 + mcol] = sS2[q];
            redS[(w * 64 + 48 + r0 + q) * 12 + mcol] = sS3[q];
        }
    }
    redGp[w * 64 + l] = gA;
    __syncthreads();

    if (tid < 64) {   // wave 0 reduces gram
        const f32x4 g = redGp[0 * 64 + l] + redGp[1 * 64 + l]
                      + redGp[2 * 64 + l] + redGp[3 * 64 + l];
        if (mcol < Mn) {
            if (r0 + 0 < Mn) redG[(r0 + 0) * Mn + mcol] = g[0];
            if (r0 + 1 < Mn) redG[(r0 + 1) * Mn + mcol] = g[1];
            if (r0 + 2 < Mn) redG[(r0 + 2) * Mn + mcol] = g[2];
            if (r0 + 3 < Mn) redG[(r0 + 3) * Mn + mcol] = g[3];
        }
    }
    __syncthreads();

    // finish: one thread per b
    if (tid < Bn) {
        const int b = tid;
        float wv[Mn];
        float numer = 0.f;
#pragma unroll
        for (int m = 0; m < Mn; ++m) {
            const float s = redS[(0 * 64 + b) * 12 + m]
                          + redS[(1 * 64 + b) * 12 + m]
                          + redS[(2 * 64 + b) * 12 + m]
                          + redS[(3 * 64 + b) * 12 + m];
            wv[m] = __expf(BETA * (s - 1.f));
            numer = fmaf(wv[m], s, numer);
        }
        float den2 = 0.f;
#pragma unroll
        for (int i = 0; i < Mn; ++i) {
            float row = 0.f;
#pragma unroll
            for (int j = 0; j < Mn; ++j) row = fmaf(wv[j], redG[i * Mn + j], row);
            den2 = fmaf(wv[i], row, den2);
        }
        out[b * Cn + c] = 100.f * numer / sqrtf(den2);
    }
}

// ---------------- fallback: self-contained single-dispatch (R21-style) ----------------
__global__ __launch_bounds__(256) void fused2_kernel(
    const float* __restrict__ img, const float* __restrict__ mem,
    float* __restrict__ out) {
    __shared__ float redS[4][Bn][12];
    __shared__ f32x4 redGp[4][64];
    __shared__ float redG[Mn * Mn];

    const int c   = blockIdx.x;
    const int tid = threadIdx.x;
    const int l   = tid & 63;
    const int w   = tid >> 6;
    const int rw  = l & 15;
    const int mrow = (rw < Mn) ? rw : 0;
    const int kb   = (l >> 4) * 8;

    const float* mc = mem + (size_t)c * (Mn * Dn) + mrow * Dn + kb;

    f32x4 accS0 = {0.f,0.f,0.f,0.f}, accS1 = {0.f,0.f,0.f,0.f};
    f32x4 accS2 = {0.f,0.f,0.f,0.f}, accS3 = {0.f,0.f,0.f,0.f};
    f32x4 accG  = {0.f,0.f,0.f,0.f};

#pragma unroll
    for (int j = 0; j < 8; ++j) {
        const int kstep = 8 * w + j;
        const float4 m0 = *reinterpret_cast<const float4*>(mc + kstep * 32);
        const float4 m1 = *reinterpret_cast<const float4*>(mc + kstep * 32 + 4);
        const bf16x8 f = pack_bf16x8(m0, m1);
        accG = __builtin_amdgcn_mfma_f32_16x16x32_bf16(f, f, accG, 0, 0, 0);
        const float* ic = img + rw * Dn + kstep * 32 + kb;
        const float4 i00 = *reinterpret_cast<const float4*>(ic);
        const float4 i01 = *reinterpret_cast<const float4*>(ic + 4);
        const float4 i10 = *reinterpret_cast<const float4*>(ic + 16 * Dn);
        const float4 i11 = *reinterpret_cast<const float4*>(ic + 16 * Dn + 4);
        const float4 i20 = *reinterpret_cast<const float4*>(ic + 32 * Dn);
        const float4 i21 = *reinterpret_cast<const float4*>(ic + 32 * Dn + 4);
        const float4 i30 = *reinterpret_cast<const float4*>(ic + 48 * Dn);
        const float4 i31 = *reinterpret_cast<const float4*>(ic + 48 * Dn + 4);
        const bf16x8 a0 = pack_bf16x8(i00, i01);
        const bf16x8 a1 = pack_bf16x8(i10, i11);
        const bf16x8 a2 = pack_bf16x8(i20, i21);
        const bf16x8 a3 = pack_bf16x8(i30, i31);
        accS0 = __builtin_amdgcn_mfma_f32_16x16x32_bf16(a0, f, accS0, 0, 0, 0);
        accS1 = __builtin_amdgcn_mfma_f32_16x16x32_bf16(a1, f, accS1, 0, 0, 0);
        accS2 = __builtin_amdgcn_mfma_f32_16x16x32_bf16(a2, f, accS2, 0, 0, 0);
        accS3 = __builtin_amdgcn_mfma_f32_16x16x32_bf16(a3, f, accS3, 0, 0, 0);
    }

    const int mcol = l & 15;
    const int r0   = (l >> 4) * 4;
    if (mcol < Mn) {
#pragma unroll
        for (int q = 0; q < 4; ++q) {
            redS[w][ 0 + r0 + q][mcol] = accS0[q];
            redS[w][16 + r0 + q][mcol] = accS1[q];
            redS[w][32 + r0 + q][mcol] = accS2[q];
            redS[w][48 + r0 + q][mcol] = accS3[q];
        }
    }
    redGp[w][l] = accG;
    __syncthreads();

    if (tid < 64) {
        const f32x4 g = redGp[0][l] + redGp[1][l] + redGp[2][l] + redGp[3][l];
        if (mcol < Mn) {
            if (r0 + 0 < Mn) redG[(r0 + 0) * Mn + mcol] = g[0];
            if (r0 + 1 < Mn) redG[(r0 + 1) * Mn + mcol] = g[1];
            if (r0 + 2 < Mn) redG[(r0 + 2) * Mn + mcol] = g[2];
            if (r0 + 3 < Mn) redG[(r0 + 3) * Mn + mcol] = g[3];
        }
    }
    __syncthreads();

    if (tid < Bn) {
        const int b = tid;
        float wv[Mn];
        float numer = 0.f;
#pragma unroll
        for (int m = 0; m < Mn; ++m) {
            const float s = redS[0][b][m] + redS[1][b][m]
                          + redS[2][b][m] + redS[3][b][m];
            wv[m] = __expf(BETA * (s - 1.f));
            numer = fmaf(wv[m], s, numer);
        }
        float den2 = 0.f;
#pragma unroll
        for (int i = 0; i < Mn; ++i) {
            float row = 0.f;
#pragma unroll
            for (int j = 0; j < Mn; ++j) row = fmaf(wv[j], redG[i * Mn + j], row);
            den2 = fmaf(wv[i], row, den2);
        }
        out[b * Cn + c] = 100.f * numer / sqrtf(den2);
    }
}

extern "C" void kernel_launch(void* const* d_in, const int* in_sizes, int n_in,
                              void* d_out, int out_size, void* d_ws, size_t ws_size,
                              hipStream_t stream) {
    const float* img = (const float*)d_in[0];  // [64][1024] f32
    const float* mem = (const float*)d_in[1];  // [1000][11][1024] f32
    float* out = (float*)d_out;                // [64][1000] f32
    (void)in_sizes; (void)n_in; (void)out_size;

    constexpr size_t IMGP_B = (size_t)4 * 32 * 64 * 16;   // 128 KB

    if (ws_size >= IMGP_B) {
        bf16x8* imgP = (bf16x8*)d_ws;
        pack_img_kernel<<<dim3(32), dim3(256), 0, stream>>>(img, imgP);
        fused5_kernel<<<dim3(Cn), dim3(256), 0, stream>>>(imgP, mem, out);
    } else {
        fused2_kernel<<<dim3(Cn), dim3(256), 0, stream>>>(img, mem, out);
    }
}